// Round 5
// baseline (313.865 us; speedup 1.0000x reference)
//
#include <hip/hip_runtime.h>

// ---------------- types ----------------
typedef __bf16 bf16x8 __attribute__((ext_vector_type(8)));
typedef float  f32x4  __attribute__((ext_vector_type(4)));
typedef unsigned short ushort8 __attribute__((ext_vector_type(8)));

#define B_ROWS 8192
#define IN_D   512
#define CTX_D  256
#define CENTER 512
#define MIN_D  768
#define FF_D   1024
#define RNN_D  1024
#define OUT_D  512
#define O2C_D  256
#define TOT_D  768

__device__ __forceinline__ unsigned short f2bf(float f) {
    unsigned int u = __builtin_bit_cast(unsigned int, f);
    u = (u + 0x7fff + ((u >> 16) & 1)) >> 16;   // RNE
    return (unsigned short)u;
}

__device__ __forceinline__ void load_lds16(const void* g, void* l) {
    __builtin_amdgcn_global_load_lds(
        (const __attribute__((address_space(1))) unsigned int*)g,
        (__attribute__((address_space(3))) unsigned int*)l, 16, 0, 0);
}

// ---------------- fused prep kernel ----------------
// blockIdx segments: [0,128) reduce_sq partials; [128,1984) weight cvt; [1984,10176) act cvt
__launch_bounds__(256)
__global__ void prep_all(const float* __restrict__ Wread, float* __restrict__ partials,
                         const float* __restrict__ Wpre, const float* __restrict__ Wx,
                         const float* __restrict__ Wh,  const float* __restrict__ Wpost,
                         unsigned short* __restrict__ WpreT, unsigned short* __restrict__ WxhT,
                         unsigned short* __restrict__ WpostT, unsigned short* __restrict__ WreadT,
                         const float* __restrict__ center, const float* __restrict__ inputs,
                         const float* __restrict__ mstate,
                         unsigned short* __restrict__ csB, unsigned short* __restrict__ miB,
                         unsigned short* __restrict__ rnB) {
    const int bid = blockIdx.x;
    const int tid = threadIdx.x;
    if (bid < 128) {
        __shared__ float red[4];
        const float* p = Wread + bid * 1024 + tid * 4;
        f32x4 v = *(const f32x4*)p;
        float s = v[0]*v[0] + v[1]*v[1] + v[2]*v[2] + v[3]*v[3];
        #pragma unroll
        for (int off = 32; off > 0; off >>= 1) s += __shfl_down(s, off, 64);
        if ((tid & 63) == 0) red[tid >> 6] = s;
        __syncthreads();
        if (tid == 0) partials[bid] = red[0] + red[1] + red[2] + red[3];
        return;
    }
    if (bid < 1984) {
        int g = (bid - 128) * 256 + tid;
        const float* W; unsigned short* out; int N, ostride;
        if (g < 98304)        { W = Wpre;  out = WpreT;        N = 1024; ostride = 768;  }
        else if (g < 229376)  { g -= 98304;  W = Wx;    out = WxhT;        N = 1024; ostride = 2048; }
        else if (g < 360448)  { g -= 229376; W = Wh;    out = WxhT + 1024; N = 1024; ostride = 2048; }
        else if (g < 458752)  { g -= 360448; W = Wpost; out = WpostT;      N = 768;  ostride = 1024; }
        else                  { g -= 458752; W = Wread; out = WreadT;      N = 256;  ostride = 512;  }
        int n  = g % N;
        int kg = g / N;
        ushort8 o;
        #pragma unroll
        for (int j = 0; j < 8; ++j)
            o[j] = f2bf(W[(long)(kg * 8 + j) * N + n]);
        *(ushort8*)(out + (long)n * ostride + kg * 8) = o;
        return;
    }
    long g = (long)(bid - 1984) * 256 + tid;
    const float* src; unsigned short* dst; int logc, ostride;
    if (g < 524288)       { src = center; dst = csB;        logc = 9;  ostride = 512;  }
    else if (g < 1048576) { g -= 524288;  src = inputs; dst = miB;        logc = 9;  ostride = 768;  }
    else                  { g -= 1048576; src = mstate; dst = rnB + 1024; logc = 10; ostride = 2048; }
    long e = g * 8;
    long row = e >> logc;
    int  col = (int)(e & ((1 << logc) - 1));
    f32x4 v0 = *(const f32x4*)(src + e);
    f32x4 v1 = *(const f32x4*)(src + e + 4);
    ushort8 o;
    o[0] = f2bf(v0[0]); o[1] = f2bf(v0[1]); o[2] = f2bf(v0[2]); o[3] = f2bf(v0[3]);
    o[4] = f2bf(v1[0]); o[5] = f2bf(v1[1]); o[6] = f2bf(v1[2]); o[7] = f2bf(v1[3]);
    *(ushort8*)(dst + row * (long)ostride + col) = o;
}

// ---------------- GEMM ----------------
// C(M x N) = act(A(M x K) @ W^T(N x K)^T [+ bias][* scale])
// Round-2 proven base: BM=128, BN=64, BK=64, 4 waves (wm=wave&1: 64 rows, wn=wave>>1: 32 cols),
// 2-barrier K-loop, A staged via global_load_lds w16 with the verified conflict-free swizzle
// (chunk (row,kg) at slot row*8 + (kg^(row&7)); measured 0 conflicts in round 2).
// NEW: B fragments read DIRECTLY global->VGPR (weights are small + L3-resident): removes
// B staging + 1/3 of LDS reads; per instruction each lane-quad reads 64 contiguous bytes.
// Grid: blockIdx.x = bm (fast) — A fetched once from HBM; B re-reads hit Infinity Cache.
// MODE 0: *clipscale (bias = 128 partials of sum(W_read^2)) -> bf16 outB   (context)
// MODE 1: bias+relu  -> bf16 outB                                           (pre)
// MODE 2: bias+tanh  -> bf16 outB + fp32 outF                               (rnn/h_new)
// MODE 3: bias+relu  -> fp32 split d_out                                    (post)
template<int MODE>
__launch_bounds__(256, 4)
__global__ void gemm_bt(const unsigned short* __restrict__ A,
                        const unsigned short* __restrict__ Bt,
                        int K, const float* __restrict__ bias,
                        unsigned short* __restrict__ outB, int ldob,
                        float* __restrict__ outF, int ldof) {
    __shared__ alignas(16) unsigned short sA[128 * 64];   // 16 KB

    const int tid  = threadIdx.x;
    const int wave = tid >> 6;
    const int lane = tid & 63;
    const int bm = blockIdx.x, bn = blockIdx.y;
    const int wm = wave & 1, wn = wave >> 1;
    const int lr = lane >> 4;   // quad id 0..3
    const int lc = lane & 15;
    const int sw = lc & 7;

    f32x4 acc[4][2] = {};

    // A staging offsets: 1024 chunks of 16B; chunk c -> row=c>>3, kg=(c&7)^(row&7)
    long aoff[4];
    #pragma unroll
    for (int j = 0; j < 4; ++j) {
        const int c   = tid + j * 256;
        const int row = c >> 3;
        const int kg  = (c & 7) ^ (row & 7);
        aoff[j] = (long)(bm * 128 + row) * K + kg * 8;
    }

    // B row base pointers (direct global reads): rows bn*64 + wn*32 + u*16 + lc
    const unsigned short* bp0 = Bt + (long)(bn * 64 + wn * 32 + lc) * K + lr * 8;
    const unsigned short* bp1 = bp0 + (long)16 * K;

    for (int k0 = 0; k0 < K; k0 += 64) {
        #pragma unroll
        for (int j = 0; j < 4; ++j)
            load_lds16(A + aoff[j] + k0, (char*)sA + j * 4096 + wave * 1024);

        // B fragments for this K-slab: issued before the barrier, land under the DMA shadow
        bf16x8 bfr[2][2];
        #pragma unroll
        for (int kh = 0; kh < 2; ++kh) {
            bfr[kh][0] = *(const bf16x8*)(bp0 + k0 + kh * 32);
            bfr[kh][1] = *(const bf16x8*)(bp1 + k0 + kh * 32);
        }
        __syncthreads();

        #pragma unroll
        for (int kh = 0; kh < 2; ++kh) {
            const int ch = (kh * 4 + lr) ^ sw;
            bf16x8 af[4];
            #pragma unroll
            for (int t = 0; t < 4; ++t)
                af[t] = *(const bf16x8*)(sA + (wm * 64 + t * 16 + lc) * 64 + ch * 8);
            #pragma unroll
            for (int i = 0; i < 4; ++i)
                #pragma unroll
                for (int u = 0; u < 2; ++u)
                    acc[i][u] = __builtin_amdgcn_mfma_f32_16x16x32_bf16(af[i], bfr[kh][u], acc[i][u], 0, 0, 0);
        }
        __syncthreads();
    }

    // epilogue: C/D layout col = lane&15, row = (lane>>4)*4 + r
    float sc = 1.f;
    if constexpr (MODE == 0) {
        float s = 0.f;
        for (int i = 0; i < 128; ++i) s += bias[i];   // partials of sum(W_read^2)
        sc = 1.f / fmaxf(sqrtf(s), 1.f);
    }
    #pragma unroll
    for (int u = 0; u < 2; ++u) {
        const int gcol = bn * 64 + wn * 32 + u * 16 + lc;
        float bv = 0.f;
        if constexpr (MODE != 0) bv = bias[gcol];
        #pragma unroll
        for (int tm = 0; tm < 4; ++tm) {
            const int grow0 = bm * 128 + wm * 64 + tm * 16 + lr * 4;
            #pragma unroll
            for (int r = 0; r < 4; ++r) {
                const long grow = grow0 + r;
                float v = acc[tm][u][r];
                if constexpr (MODE == 0) v *= sc;
                else v += bv;
                if constexpr (MODE == 1 || MODE == 3) v = fmaxf(v, 0.f);
                if constexpr (MODE == 2) v = tanhf(v);
                if constexpr (MODE == 0 || MODE == 1 || MODE == 2)
                    outB[grow * (long)ldob + gcol] = f2bf(v);
                if constexpr (MODE == 2)
                    outF[grow * (long)ldof + gcol] = v;
                if constexpr (MODE == 3) {
                    if (gcol < OUT_D)
                        outF[grow * OUT_D + gcol] = v;
                    else
                        outF[(long)B_ROWS * OUT_D + grow * O2C_D + (gcol - OUT_D)] = v;
                }
            }
        }
    }
}

// ---------------- launch ----------------
extern "C" void kernel_launch(void* const* d_in, const int* in_sizes, int n_in,
                              void* d_out, int out_size, void* d_ws, size_t ws_size,
                              hipStream_t stream) {
    const float* inputs = (const float*)d_in[0];
    const float* center = (const float*)d_in[1];
    const float* mstate = (const float*)d_in[2];
    const float* W_read = (const float*)d_in[3];
    const float* W_pre  = (const float*)d_in[4];
    const float* b_pre  = (const float*)d_in[5];
    const float* Wx     = (const float*)d_in[6];
    const float* Wh     = (const float*)d_in[7];
    const float* b_rnn  = (const float*)d_in[8];
    const float* W_post = (const float*)d_in[9];
    const float* b_post = (const float*)d_in[10];
    float* out = (float*)d_out;

    char* ws = (char*)d_ws;
    float* partials = (float*)ws;                                  // 128 floats
    unsigned short* WreadT = (unsigned short*)(ws + 1024);         // 256 x 512
    unsigned short* WpreT  = WreadT + 256 * 512;                   // 1024 x 768
    unsigned short* WxhT   = WpreT  + 1024 * 768;                  // 1024 x 2048
    unsigned short* WpostT = WxhT   + (long)1024 * 2048;           // 768 x 1024
    unsigned short* csB    = WpostT + 768 * 1024;                  // 8192 x 512
    unsigned short* miB    = csB + (long)B_ROWS * CENTER;          // 8192 x 768  [inputs | ctx]
    unsigned short* rnB    = miB + (long)B_ROWS * MIN_D;           // 8192 x 2048 [rnn_in | ms]
    unsigned short* hB     = rnB + (long)B_ROWS * 2048;            // 8192 x 1024

    prep_all<<<10176, 256, 0, stream>>>(W_read, partials,
                                        W_pre, Wx, Wh, W_post,
                                        WpreT, WxhT, WpostT, WreadT,
                                        center, inputs, mstate, csB, miB, rnB);

    // L1: context = (cs @ W_read) * clipscale -> miB cols [512..767]
    gemm_bt<0><<<dim3(64, 4), 256, 0, stream>>>(csB, WreadT, 512, partials,
                                                miB + 512, MIN_D, nullptr, 0);
    // L2: rnn_in = relu(mi @ W_pre + b_pre) -> rnB cols [0..1023]
    gemm_bt<1><<<dim3(64, 16), 256, 0, stream>>>(miB, WpreT, 768, b_pre,
                                                 rnB, 2048, nullptr, 0);
    // L3: h = tanh([rnn_in|ms] @ [Wx;Wh] + b_rnn) -> hB (bf16) + d_out region 2 (fp32)
    gemm_bt<2><<<dim3(64, 16), 256, 0, stream>>>(rnB, WxhT, 2048, b_rnn,
                                                 hB, RNN_D,
                                                 out + (long)B_ROWS * TOT_D, RNN_D);
    // L4: module_output = relu(h @ W_post + b_post) -> fp32 d_out regions 0/1
    gemm_bt<3><<<dim3(64, 12), 256, 0, stream>>>(hB, WpostT, 1024, b_post,
                                                 nullptr, 0, out, 0);
}

// Round 6
// 248.984 us; speedup vs baseline: 1.2606x; 1.2606x over previous
//
#include <hip/hip_runtime.h>

// ---------------- types ----------------
typedef __bf16 bf16x8 __attribute__((ext_vector_type(8)));
typedef float  f32x4  __attribute__((ext_vector_type(4)));
typedef unsigned short ushort8 __attribute__((ext_vector_type(8)));

#define B_ROWS 8192
#define IN_D   512
#define CTX_D  256
#define CENTER 512
#define MIN_D  768
#define FF_D   1024
#define RNN_D  1024
#define OUT_D  512
#define O2C_D  256
#define TOT_D  768

__device__ __forceinline__ unsigned short f2bf(float f) {
    unsigned int u = __builtin_bit_cast(unsigned int, f);
    u = (u + 0x7fff + ((u >> 16) & 1)) >> 16;   // RNE
    return (unsigned short)u;
}

__device__ __forceinline__ void load_lds16(const void* g, void* l) {
    __builtin_amdgcn_global_load_lds(
        (const __attribute__((address_space(1))) unsigned int*)g,
        (__attribute__((address_space(3))) unsigned int*)l, 16, 0, 0);
}

// ---------------- fused prep kernel ----------------
// blockIdx segments: [0,128) reduce_sq partials; [128,1984) weight cvt; [1984,10176) act cvt
__launch_bounds__(256)
__global__ void prep_all(const float* __restrict__ Wread, float* __restrict__ partials,
                         const float* __restrict__ Wpre, const float* __restrict__ Wx,
                         const float* __restrict__ Wh,  const float* __restrict__ Wpost,
                         unsigned short* __restrict__ WpreT, unsigned short* __restrict__ WxhT,
                         unsigned short* __restrict__ WpostT, unsigned short* __restrict__ WreadT,
                         const float* __restrict__ center, const float* __restrict__ inputs,
                         const float* __restrict__ mstate,
                         unsigned short* __restrict__ csB, unsigned short* __restrict__ miB,
                         unsigned short* __restrict__ rnB) {
    const int bid = blockIdx.x;
    const int tid = threadIdx.x;
    if (bid < 128) {
        __shared__ float red[4];
        const float* p = Wread + bid * 1024 + tid * 4;
        f32x4 v = *(const f32x4*)p;
        float s = v[0]*v[0] + v[1]*v[1] + v[2]*v[2] + v[3]*v[3];
        #pragma unroll
        for (int off = 32; off > 0; off >>= 1) s += __shfl_down(s, off, 64);
        if ((tid & 63) == 0) red[tid >> 6] = s;
        __syncthreads();
        if (tid == 0) partials[bid] = red[0] + red[1] + red[2] + red[3];
        return;
    }
    if (bid < 1984) {
        int g = (bid - 128) * 256 + tid;
        const float* W; unsigned short* out; int N, ostride;
        if (g < 98304)        { W = Wpre;  out = WpreT;        N = 1024; ostride = 768;  }
        else if (g < 229376)  { g -= 98304;  W = Wx;    out = WxhT;        N = 1024; ostride = 2048; }
        else if (g < 360448)  { g -= 229376; W = Wh;    out = WxhT + 1024; N = 1024; ostride = 2048; }
        else if (g < 458752)  { g -= 360448; W = Wpost; out = WpostT;      N = 768;  ostride = 1024; }
        else                  { g -= 458752; W = Wread; out = WreadT;      N = 256;  ostride = 512;  }
        int n  = g % N;
        int kg = g / N;
        ushort8 o;
        #pragma unroll
        for (int j = 0; j < 8; ++j)
            o[j] = f2bf(W[(long)(kg * 8 + j) * N + n]);
        *(ushort8*)(out + (long)n * ostride + kg * 8) = o;
        return;
    }
    long g = (long)(bid - 1984) * 256 + tid;
    const float* src; unsigned short* dst; int logc, ostride;
    if (g < 524288)       { src = center; dst = csB;        logc = 9;  ostride = 512;  }
    else if (g < 1048576) { g -= 524288;  src = inputs; dst = miB;        logc = 9;  ostride = 768;  }
    else                  { g -= 1048576; src = mstate; dst = rnB + 1024; logc = 10; ostride = 2048; }
    long e = g * 8;
    long row = e >> logc;
    int  col = (int)(e & ((1 << logc) - 1));
    f32x4 v0 = *(const f32x4*)(src + e);
    f32x4 v1 = *(const f32x4*)(src + e + 4);
    ushort8 o;
    o[0] = f2bf(v0[0]); o[1] = f2bf(v0[1]); o[2] = f2bf(v0[2]); o[3] = f2bf(v0[3]);
    o[4] = f2bf(v1[0]); o[5] = f2bf(v1[1]); o[6] = f2bf(v1[2]); o[7] = f2bf(v1[3]);
    *(ushort8*)(dst + row * (long)ostride + col) = o;
}

// ---------------- GEMM ----------------
// C(M x N) = act(A(M x K) @ W^T(N x K)^T [+ bias][* scale])
// Round-2 verified base widened to BN=128: BM=128, BN=128, BK=64.
// 4 waves, each computes 64x64 (wm=wave&1 rows, wn=wave>>1 cols).
// FLOP/staged-byte = 128*128/(128+128) = 64 (was 42.7) — staging-BW model says
// this is the lever; all else (swizzle, bm-fast grid, 2-barrier loop) unchanged.
// Swizzle (verified 0 conflicts in r2): 16B chunk (row,kg) at slot row*8 + (kg^(row&7));
// staging thread c fetches kg=(c&7)^((c>>3)&7); read chunk = (kh*4+lr)^(lc&7).
// Grid: blockIdx.x = bm (fast) -> consecutive blocks share the B tile (L2-resident).
// MODE 0: *clipscale (bias = 128 partials of sum(W_read^2)) -> bf16 outB   (context)
// MODE 1: bias+relu  -> bf16 outB                                           (pre)
// MODE 2: bias+tanh  -> bf16 outB + fp32 outF                               (rnn/h_new)
// MODE 3: bias+relu  -> fp32 split d_out                                    (post)
template<int MODE>
__launch_bounds__(256, 2)
__global__ void gemm_bt(const unsigned short* __restrict__ A,
                        const unsigned short* __restrict__ Bt,
                        int K, const float* __restrict__ bias,
                        unsigned short* __restrict__ outB, int ldob,
                        float* __restrict__ outF, int ldof) {
    __shared__ alignas(16) unsigned short sA[128 * 64];   // 16 KB
    __shared__ alignas(16) unsigned short sB[128 * 64];   // 16 KB

    const int tid  = threadIdx.x;
    const int wave = tid >> 6;
    const int lane = tid & 63;
    const int bm = blockIdx.x, bn = blockIdx.y;
    const int wm = wave & 1, wn = wave >> 1;
    const int lr = lane >> 4;   // quad id 0..3
    const int lc = lane & 15;
    const int sw = lc & 7;

    f32x4 acc[4][4] = {};

    // staging offsets: 1024 chunks of 16B per matrix; chunk c -> row=c>>3, kg=(c&7)^(row&7)
    long aoff[4], boff[4];
    #pragma unroll
    for (int j = 0; j < 4; ++j) {
        const int c   = tid + j * 256;
        const int row = c >> 3;
        const int kg  = (c & 7) ^ (row & 7);
        aoff[j] = (long)(bm * 128 + row) * K + kg * 8;
        boff[j] = (long)(bn * 128 + row) * K + kg * 8;
    }

    for (int k0 = 0; k0 < K; k0 += 64) {
        #pragma unroll
        for (int j = 0; j < 4; ++j) {
            load_lds16(A  + aoff[j] + k0, (char*)sA + j * 4096 + wave * 1024);
            load_lds16(Bt + boff[j] + k0, (char*)sB + j * 4096 + wave * 1024);
        }
        __syncthreads();

        #pragma unroll
        for (int kh = 0; kh < 2; ++kh) {
            const int ch = (kh * 4 + lr) ^ sw;
            bf16x8 af[4], bfr[4];
            #pragma unroll
            for (int t = 0; t < 4; ++t) {
                af[t]  = *(const bf16x8*)(sA + (wm * 64 + t * 16 + lc) * 64 + ch * 8);
                bfr[t] = *(const bf16x8*)(sB + (wn * 64 + t * 16 + lc) * 64 + ch * 8);
            }
            #pragma unroll
            for (int i = 0; i < 4; ++i)
                #pragma unroll
                for (int u = 0; u < 4; ++u)
                    acc[i][u] = __builtin_amdgcn_mfma_f32_16x16x32_bf16(af[i], bfr[u], acc[i][u], 0, 0, 0);
        }
        __syncthreads();
    }

    // epilogue: C/D layout col = lane&15, row = (lane>>4)*4 + r
    float sc = 1.f;
    if constexpr (MODE == 0) {
        float s = 0.f;
        for (int i = 0; i < 128; ++i) s += bias[i];   // partials of sum(W_read^2)
        sc = 1.f / fmaxf(sqrtf(s), 1.f);
    }
    #pragma unroll
    for (int u = 0; u < 4; ++u) {
        const int gcol = bn * 128 + wn * 64 + u * 16 + lc;
        float bv = 0.f;
        if constexpr (MODE != 0) bv = bias[gcol];
        #pragma unroll
        for (int tm = 0; tm < 4; ++tm) {
            const int grow0 = bm * 128 + wm * 64 + tm * 16 + lr * 4;
            #pragma unroll
            for (int r = 0; r < 4; ++r) {
                const long grow = grow0 + r;
                float v = acc[tm][u][r];
                if constexpr (MODE == 0) v *= sc;
                else v += bv;
                if constexpr (MODE == 1 || MODE == 3) v = fmaxf(v, 0.f);
                if constexpr (MODE == 2) v = tanhf(v);
                if constexpr (MODE == 0 || MODE == 1 || MODE == 2)
                    outB[grow * (long)ldob + gcol] = f2bf(v);
                if constexpr (MODE == 2)
                    outF[grow * (long)ldof + gcol] = v;
                if constexpr (MODE == 3) {
                    if (gcol < OUT_D)
                        outF[grow * OUT_D + gcol] = v;
                    else
                        outF[(long)B_ROWS * OUT_D + grow * O2C_D + (gcol - OUT_D)] = v;
                }
            }
        }
    }
}

// ---------------- launch ----------------
extern "C" void kernel_launch(void* const* d_in, const int* in_sizes, int n_in,
                              void* d_out, int out_size, void* d_ws, size_t ws_size,
                              hipStream_t stream) {
    const float* inputs = (const float*)d_in[0];
    const float* center = (const float*)d_in[1];
    const float* mstate = (const float*)d_in[2];
    const float* W_read = (const float*)d_in[3];
    const float* W_pre  = (const float*)d_in[4];
    const float* b_pre  = (const float*)d_in[5];
    const float* Wx     = (const float*)d_in[6];
    const float* Wh     = (const float*)d_in[7];
    const float* b_rnn  = (const float*)d_in[8];
    const float* W_post = (const float*)d_in[9];
    const float* b_post = (const float*)d_in[10];
    float* out = (float*)d_out;

    char* ws = (char*)d_ws;
    float* partials = (float*)ws;                                  // 128 floats
    unsigned short* WreadT = (unsigned short*)(ws + 1024);         // 256 x 512
    unsigned short* WpreT  = WreadT + 256 * 512;                   // 1024 x 768
    unsigned short* WxhT   = WpreT  + 1024 * 768;                  // 1024 x 2048
    unsigned short* WpostT = WxhT   + (long)1024 * 2048;           // 768 x 1024
    unsigned short* csB    = WpostT + 768 * 1024;                  // 8192 x 512
    unsigned short* miB    = csB + (long)B_ROWS * CENTER;          // 8192 x 768  [inputs | ctx]
    unsigned short* rnB    = miB + (long)B_ROWS * MIN_D;           // 8192 x 2048 [rnn_in | ms]
    unsigned short* hB     = rnB + (long)B_ROWS * 2048;            // 8192 x 1024

    prep_all<<<10176, 256, 0, stream>>>(W_read, partials,
                                        W_pre, Wx, Wh, W_post,
                                        WpreT, WxhT, WpostT, WreadT,
                                        center, inputs, mstate, csB, miB, rnB);

    // L1: context = (cs @ W_read) * clipscale -> miB cols [512..767]
    gemm_bt<0><<<dim3(64, 2), 256, 0, stream>>>(csB, WreadT, 512, partials,
                                                miB + 512, MIN_D, nullptr, 0);
    // L2: rnn_in = relu(mi @ W_pre + b_pre) -> rnB cols [0..1023]
    gemm_bt<1><<<dim3(64, 8), 256, 0, stream>>>(miB, WpreT, 768, b_pre,
                                                rnB, 2048, nullptr, 0);
    // L3: h = tanh([rnn_in|ms] @ [Wx;Wh] + b_rnn) -> hB (bf16) + d_out region 2 (fp32)
    gemm_bt<2><<<dim3(64, 8), 256, 0, stream>>>(rnB, WxhT, 2048, b_rnn,
                                                hB, RNN_D,
                                                out + (long)B_ROWS * TOT_D, RNN_D);
    // L4: module_output = relu(h @ W_post + b_post) -> fp32 d_out regions 0/1
    gemm_bt<3><<<dim3(64, 6), 256, 0, stream>>>(hB, WpostT, 1024, b_post,
                                                nullptr, 0, out, 0);
}

// Round 7
// 239.848 us; speedup vs baseline: 1.3086x; 1.0381x over previous
//
#include <hip/hip_runtime.h>

// ---------------- types ----------------
typedef __bf16 bf16x8 __attribute__((ext_vector_type(8)));
typedef float  f32x4  __attribute__((ext_vector_type(4)));
typedef unsigned short ushort8 __attribute__((ext_vector_type(8)));

#define B_ROWS 8192
#define OUT_D  512
#define O2C_D  256
#define TOT_D  768
#define MIN_D  768
#define RNN_D  1024

__device__ __forceinline__ unsigned short f2bf(float f) {
    unsigned int u = __builtin_bit_cast(unsigned int, f);
    u = (u + 0x7fff + ((u >> 16) & 1)) >> 16;   // RNE
    return (unsigned short)u;
}

__device__ __forceinline__ void load_lds16(const void* g, void* l) {
    __builtin_amdgcn_global_load_lds(
        (const __attribute__((address_space(1))) unsigned int*)g,
        (__attribute__((address_space(3))) unsigned int*)l, 16, 0, 0);
}

// ---------------- fused prep kernel ----------------
// blockIdx segments: [0,128) reduce_sq partials; [128,1984) weight cvt; [1984,10176) act cvt
__launch_bounds__(256)
__global__ void prep_all(const float* __restrict__ Wread, float* __restrict__ partials,
                         const float* __restrict__ Wpre, const float* __restrict__ Wx,
                         const float* __restrict__ Wh,  const float* __restrict__ Wpost,
                         unsigned short* __restrict__ WpreT, unsigned short* __restrict__ WxhT,
                         unsigned short* __restrict__ WpostT, unsigned short* __restrict__ WreadT,
                         const float* __restrict__ center, const float* __restrict__ inputs,
                         const float* __restrict__ mstate,
                         unsigned short* __restrict__ csB, unsigned short* __restrict__ miB,
                         unsigned short* __restrict__ rnB) {
    const int bid = blockIdx.x;
    const int tid = threadIdx.x;
    if (bid < 128) {
        __shared__ float red[4];
        const float* p = Wread + bid * 1024 + tid * 4;
        f32x4 v = *(const f32x4*)p;
        float s = v[0]*v[0] + v[1]*v[1] + v[2]*v[2] + v[3]*v[3];
        #pragma unroll
        for (int off = 32; off > 0; off >>= 1) s += __shfl_down(s, off, 64);
        if ((tid & 63) == 0) red[tid >> 6] = s;
        __syncthreads();
        if (tid == 0) partials[bid] = red[0] + red[1] + red[2] + red[3];
        return;
    }
    if (bid < 1984) {
        int g = (bid - 128) * 256 + tid;
        const float* W; unsigned short* out; int N, ostride;
        if (g < 98304)        { W = Wpre;  out = WpreT;        N = 1024; ostride = 768;  }
        else if (g < 229376)  { g -= 98304;  W = Wx;    out = WxhT;        N = 1024; ostride = 2048; }
        else if (g < 360448)  { g -= 229376; W = Wh;    out = WxhT + 1024; N = 1024; ostride = 2048; }
        else if (g < 458752)  { g -= 360448; W = Wpost; out = WpostT;      N = 768;  ostride = 1024; }
        else                  { g -= 458752; W = Wread; out = WreadT;      N = 256;  ostride = 512;  }
        int n  = g % N;
        int kg = g / N;
        ushort8 o;
        #pragma unroll
        for (int j = 0; j < 8; ++j)
            o[j] = f2bf(W[(long)(kg * 8 + j) * N + n]);
        *(ushort8*)(out + (long)n * ostride + kg * 8) = o;
        return;
    }
    long g = (long)(bid - 1984) * 256 + tid;
    const float* src; unsigned short* dst; int logc, ostride;
    if (g < 524288)       { src = center; dst = csB;        logc = 9;  ostride = 512;  }
    else if (g < 1048576) { g -= 524288;  src = inputs; dst = miB;        logc = 9;  ostride = 768;  }
    else                  { g -= 1048576; src = mstate; dst = rnB + 1024; logc = 10; ostride = 2048; }
    long e = g * 8;
    long row = e >> logc;
    int  col = (int)(e & ((1 << logc) - 1));
    f32x4 v0 = *(const f32x4*)(src + e);
    f32x4 v1 = *(const f32x4*)(src + e + 4);
    ushort8 o;
    o[0] = f2bf(v0[0]); o[1] = f2bf(v0[1]); o[2] = f2bf(v0[2]); o[3] = f2bf(v0[3]);
    o[4] = f2bf(v1[0]); o[5] = f2bf(v1[1]); o[6] = f2bf(v1[2]); o[7] = f2bf(v1[3]);
    *(ushort8*)(dst + row * (long)ostride + col) = o;
}

// ---------------- GEMM ----------------
// C(M x N) = act(A(M x K) @ W^T(N x K)^T [+ bias][* scale])
// BM=128, BNT in {64,128}, BK=64. 4 waves: wm=wave&1 (64 rows), wn=wave>>1 (BNT/2 cols).
// Verified conflict-free swizzle (r2/r6: 0 conflicts): chunk (row,kg) at slot
// row*8 + (kg^(row&7)); read chunk = (kh*4+lr)^(lc&7).
// Grid: blockIdx.x = bm (fast) -> B tile L2/L3-resident across consecutive blocks.
// Epilogue: stage activated C tile in LDS (K-loop buffers are free), then write
// full 128B lines cooperatively (consecutive lanes -> consecutive addresses).
// MODE 0: *clipscale (bias = 128 partials of sum(W_read^2)) -> bf16  (context, BNT=64)
// MODE 1: bias+relu -> bf16                                           (pre,     BNT=128)
// MODE 2: bias+tanh -> bf16 + fp32                                    (rnn,     BNT=64)
// MODE 3: bias+relu -> fp32 split to d_out regions 0/1                (post,    BNT=64)
template<int MODE, int BNT>
__launch_bounds__(256, 4)
__global__ void gemm_bt(const unsigned short* __restrict__ A,
                        const unsigned short* __restrict__ Bt,
                        int K, const float* __restrict__ bias,
                        unsigned short* __restrict__ outB, int ldob,
                        float* __restrict__ outF, int ldof) {
    constexpr int U   = BNT / 32;        // B fragments per wave (col tiles of 16)
    constexpr int BJ  = BNT / 32;        // B staging chunks per thread
    __shared__ alignas(16) unsigned short smem[128 * 64 + BNT * 64];
    unsigned short* sA = smem;
    unsigned short* sB = smem + 128 * 64;

    const int tid  = threadIdx.x;
    const int wave = tid >> 6;
    const int lane = tid & 63;
    const int bm = blockIdx.x, bn = blockIdx.y;
    const int wm = wave & 1, wn = wave >> 1;
    const int lr = lane >> 4;   // quad id 0..3
    const int lc = lane & 15;
    const int sw = lc & 7;

    f32x4 acc[4][U] = {};

    long aoff[4], boff[BJ];
    #pragma unroll
    for (int j = 0; j < 4; ++j) {
        const int c   = tid + j * 256;
        const int row = c >> 3;
        const int kg  = (c & 7) ^ (row & 7);
        aoff[j] = (long)(bm * 128 + row) * K + kg * 8;
    }
    #pragma unroll
    for (int j = 0; j < BJ; ++j) {
        const int c   = tid + j * 256;
        const int row = c >> 3;
        const int kg  = (c & 7) ^ (row & 7);
        boff[j] = (long)(bn * BNT + row) * K + kg * 8;
    }

    for (int k0 = 0; k0 < K; k0 += 64) {
        #pragma unroll
        for (int j = 0; j < 4; ++j)
            load_lds16(A + aoff[j] + k0, (char*)sA + j * 4096 + wave * 1024);
        #pragma unroll
        for (int j = 0; j < BJ; ++j)
            load_lds16(Bt + boff[j] + k0, (char*)sB + j * 4096 + wave * 1024);
        __syncthreads();

        #pragma unroll
        for (int kh = 0; kh < 2; ++kh) {
            const int ch = (kh * 4 + lr) ^ sw;
            bf16x8 af[4], bfr[U];
            #pragma unroll
            for (int t = 0; t < 4; ++t)
                af[t] = *(const bf16x8*)(sA + (wm * 64 + t * 16 + lc) * 64 + ch * 8);
            #pragma unroll
            for (int u = 0; u < U; ++u)
                bfr[u] = *(const bf16x8*)(sB + (wn * (BNT / 2) + u * 16 + lc) * 64 + ch * 8);
            #pragma unroll
            for (int i = 0; i < 4; ++i)
                #pragma unroll
                for (int u = 0; u < U; ++u)
                    acc[i][u] = __builtin_amdgcn_mfma_f32_16x16x32_bf16(af[i], bfr[u], acc[i][u], 0, 0, 0);
        }
        __syncthreads();
    }

    // ---- activation in registers (C/D layout: col=lane&15, row=quad*4+r) ----
    float sc = 1.f;
    if constexpr (MODE == 0) {
        float s = 0.f;
        for (int i = 0; i < 128; ++i) s += bias[i];
        sc = 1.f / fmaxf(sqrtf(s), 1.f);
    }
    #pragma unroll
    for (int u = 0; u < U; ++u) {
        float bv = 0.f;
        if constexpr (MODE != 0) bv = bias[bn * BNT + wn * (BNT / 2) + u * 16 + lc];
        #pragma unroll
        for (int tm = 0; tm < 4; ++tm)
            #pragma unroll
            for (int r = 0; r < 4; ++r) {
                float v = acc[tm][u][r];
                if constexpr (MODE == 0) v *= sc;
                else v += bv;
                if constexpr (MODE == 1 || MODE == 3) v = fmaxf(v, 0.f);
                if constexpr (MODE == 2) v = tanhf(v);
                acc[tm][u][r] = v;
            }
    }

    const int ctcol = wn * (BNT / 2); // wave's col base within tile

    // ---- phase 1: bf16 output (MODE 0,1,2) via LDS, full-line writes ----
    if constexpr (MODE <= 2) {
        unsigned short* Cb = smem;   // 128 x BNT bf16 tile
        #pragma unroll
        for (int u = 0; u < U; ++u)
            #pragma unroll
            for (int tm = 0; tm < 4; ++tm)
                #pragma unroll
                for (int r = 0; r < 4; ++r)
                    Cb[(wm * 64 + tm * 16 + lr * 4 + r) * BNT + ctcol + u * 16 + lc] =
                        f2bf(acc[tm][u][r]);
        __syncthreads();
        constexpr int RC = BNT / 8;            // 16B chunks per row
        constexpr int CPT = 128 * RC / 256;    // chunks per thread
        #pragma unroll
        for (int t = 0; t < CPT; ++t) {
            const int chunk = t * 256 + tid;
            const int row = chunk / RC;
            const int c8  = chunk % RC;
            ushort8 val = *(ushort8*)(Cb + row * BNT + c8 * 8);
            *(ushort8*)(outB + (long)(bm * 128 + row) * ldob + bn * BNT + c8 * 8) = val;
        }
    }

    // ---- phase 2: fp32 output (MODE 2,3) via LDS, two 64-row halves ----
    if constexpr (MODE == 2 || MODE == 3) {
        float* Cf = (float*)smem;   // 64 x BNT fp32 half tile
        #pragma unroll
        for (int h = 0; h < 2; ++h) {
            __syncthreads();
            if (wm == h) {
                #pragma unroll
                for (int u = 0; u < U; ++u)
                    #pragma unroll
                    for (int tm = 0; tm < 4; ++tm)
                        #pragma unroll
                        for (int r = 0; r < 4; ++r)
                            Cf[(tm * 16 + lr * 4 + r) * BNT + ctcol + u * 16 + lc] =
                                acc[tm][u][r];
            }
            __syncthreads();
            constexpr int RCF = BNT / 4;           // f32x4 chunks per row
            constexpr int CPTF = 64 * RCF / 256;   // chunks per thread
            #pragma unroll
            for (int t = 0; t < CPTF; ++t) {
                const int chunk = t * 256 + tid;
                const int row = chunk / RCF;
                const int c4  = chunk % RCF;
                f32x4 val = *(f32x4*)(Cf + row * BNT + c4 * 4);
                const long grow = bm * 128 + h * 64 + row;
                if constexpr (MODE == 2) {
                    *(f32x4*)(outF + grow * ldof + bn * BNT + c4 * 4) = val;
                } else {
                    // BNT=64: tile entirely inside one region
                    if (bn < 8)
                        *(f32x4*)(outF + grow * OUT_D + bn * 64 + c4 * 4) = val;
                    else
                        *(f32x4*)(outF + (long)B_ROWS * OUT_D + grow * O2C_D
                                  + (bn - 8) * 64 + c4 * 4) = val;
                }
            }
        }
    }
}

// ---------------- launch ----------------
extern "C" void kernel_launch(void* const* d_in, const int* in_sizes, int n_in,
                              void* d_out, int out_size, void* d_ws, size_t ws_size,
                              hipStream_t stream) {
    const float* inputs = (const float*)d_in[0];
    const float* center = (const float*)d_in[1];
    const float* mstate = (const float*)d_in[2];
    const float* W_read = (const float*)d_in[3];
    const float* W_pre  = (const float*)d_in[4];
    const float* b_pre  = (const float*)d_in[5];
    const float* Wx     = (const float*)d_in[6];
    const float* Wh     = (const float*)d_in[7];
    const float* b_rnn  = (const float*)d_in[8];
    const float* W_post = (const float*)d_in[9];
    const float* b_post = (const float*)d_in[10];
    float* out = (float*)d_out;

    char* ws = (char*)d_ws;
    float* partials = (float*)ws;                                  // 128 floats
    unsigned short* WreadT = (unsigned short*)(ws + 1024);         // 256 x 512
    unsigned short* WpreT  = WreadT + 256 * 512;                   // 1024 x 768
    unsigned short* WxhT   = WpreT  + 1024 * 768;                  // 1024 x 2048
    unsigned short* WpostT = WxhT   + (long)1024 * 2048;           // 768 x 1024
    unsigned short* csB    = WpostT + 768 * 1024;                  // 8192 x 512
    unsigned short* miB    = csB + (long)B_ROWS * 512;             // 8192 x 768  [inputs | ctx]
    unsigned short* rnB    = miB + (long)B_ROWS * MIN_D;           // 8192 x 2048 [rnn_in | ms]
    unsigned short* hB     = rnB + (long)B_ROWS * 2048;            // 8192 x 1024

    prep_all<<<10176, 256, 0, stream>>>(W_read, partials,
                                        W_pre, Wx, Wh, W_post,
                                        WpreT, WxhT, WpostT, WreadT,
                                        center, inputs, mstate, csB, miB, rnB);

    // L1: context = (cs @ W_read) * clipscale -> miB cols [512..767]
    gemm_bt<0, 64><<<dim3(64, 4), 256, 0, stream>>>(csB, WreadT, 512, partials,
                                                    miB + 512, MIN_D, nullptr, 0);
    // L2: rnn_in = relu(mi @ W_pre + b_pre) -> rnB cols [0..1023]
    gemm_bt<1, 128><<<dim3(64, 8), 256, 0, stream>>>(miB, WpreT, 768, b_pre,
                                                     rnB, 2048, nullptr, 0);
    // L3: h = tanh([rnn_in|ms] @ [Wx;Wh] + b_rnn) -> hB (bf16) + d_out region 2 (fp32)
    gemm_bt<2, 64><<<dim3(64, 16), 256, 0, stream>>>(rnB, WxhT, 2048, b_rnn,
                                                     hB, RNN_D,
                                                     out + (long)B_ROWS * TOT_D, RNN_D);
    // L4: module_output = relu(h @ W_post + b_post) -> fp32 d_out regions 0/1
    gemm_bt<3, 64><<<dim3(64, 12), 256, 0, stream>>>(hB, WpostT, 1024, b_post,
                                                     nullptr, 0, out, 0);
}